// Round 8
// baseline (294.657 us; speedup 1.0000x reference)
//
#include <hip/hip_runtime.h>
#include <math.h>

#define B_ 8
#define N_ 20000
#define K_ 128
#define C_ 256

static_assert(N_ % 32 == 0, "N must be multiple of 32");

constexpr float LMBDA = 100.0f;
constexpr float EPS_EV = 1e-10f;

typedef unsigned int u32x4 __attribute__((ext_vector_type(4)));
typedef short short8_t __attribute__((ext_vector_type(8)));
typedef float f32x4 __attribute__((ext_vector_type(4)));

// Split two fp32 into bf16 hi-plane (truncation; residual exact) and
// bf16 lo-plane (RNE of residual). Packed as (x1|x0) u32 words.
static __device__ inline void split2(float x0, float x1, unsigned& h, unsigned& l) {
  unsigned u0 = __builtin_bit_cast(unsigned, x0);
  unsigned u1 = __builtin_bit_cast(unsigned, x1);
  h = __builtin_amdgcn_perm(u1, u0, 0x07060302u);  // top16(x1)<<16 | top16(x0)
  float r0 = x0 - __builtin_bit_cast(float, u0 & 0xFFFF0000u);  // exact
  float r1 = x1 - __builtin_bit_cast(float, u1 & 0xFFFF0000u);  // exact
  unsigned v0 = __builtin_bit_cast(unsigned, r0);
  unsigned v1 = __builtin_bit_cast(unsigned, r1);
  v0 += 0x7FFFu + ((v0 >> 16) & 1u);  // RNE to bf16
  v1 += 0x7FFFu + ((v1 >> 16) & 1u);
  l = __builtin_amdgcn_perm(v1, v0, 0x07060302u);
}

// publish LDS writes + retire LDS reads, then raw barrier (global prefetch
// loads stay in flight across it -- no vmcnt drain).
#define KFENCE()                                              \
  do {                                                        \
    asm volatile("s_waitcnt lgkmcnt(0)" ::: "memory");        \
    __builtin_amdgcn_sched_barrier(0);                        \
    __builtin_amdgcn_s_barrier();                             \
    __builtin_amdgcn_sched_barrier(0);                        \
  } while (0)

// ---------------------------------------------------------------------------
// Kernel 1: projection GEMM, bf16x3 split MFMA.
// A (E rows) loaded global->registers directly in MFMA fragment layout
// (no LDS round-trip). B (F) staged through LDS in fragment-linear layout:
// staging thread (cl,g) loads F[8g..8g+7][c0+cl], splits, writes one 16B
// slot per plane at slot=(cl>>4)*64+g*16+(cl&15); consumer lane reads
// ds_read_b128 at base+lane*16 -- conflict-free both sides by construction.
// 256 thr / 4 waves (wave wm owns m-rows wm*32..+31), 64-col tile,
// 16 KB LDS double-buffered, 4 blocks/CU.
// ---------------------------------------------------------------------------
__global__ __launch_bounds__(256, 4)
void proj_mfma(const float* __restrict__ feat_x, const float* __restrict__ feat_y,
               const float* __restrict__ evx, const float* __restrict__ evy,
               float* __restrict__ part, int Sa, int chunk) {
  const int bm = blockIdx.z;
  const int b = bm >> 1, mat = bm & 1;
  const float* __restrict__ E = (mat ? evy : evx) + (size_t)b * K_ * N_;
  const float* __restrict__ F = (mat ? feat_y : feat_x) + (size_t)b * N_ * C_;
  const int c0 = blockIdx.x << 6;          // 4 c-blocks x 64 cols
  const int s = blockIdx.y;
  const int nb = s * chunk;
  const int ne = min(N_, nb + chunk);
  const int nt = (ne - nb) >> 5;

  __shared__ unsigned int BhL[2][1024];    // [buf][slot*4+j], slot=ct*64+oct*16+cr
  __shared__ unsigned int BlL[2][1024];

  const int t = threadIdx.x;
  const int lane = t & 63;
  const int wm = t >> 6;                   // wave id = m-tile AND staging octet
  const int lr = lane & 15, lg = lane >> 4;

  // B staging map: column cl, n-octet g
  const int cl = lane;
  const int g = wm;
  const int slot4 = (((cl >> 4) << 6) + (g << 4) + (cl & 15)) << 2;  // u32 index

  // A fragment map: rows wm*32 + mt*16 + lr, k-octet lg
  const size_t arow = (size_t)((wm << 5) + lr) * N_;
  const int kofs = lg << 3;

  f32x4 acc[2][4];
#pragma unroll
  for (int i = 0; i < 2; ++i)
#pragma unroll
    for (int j = 0; j < 4; ++j) acc[i][j] = (f32x4){0.f, 0.f, 0.f, 0.f};

  float4 PAe[4], PAo[4];                   // A raw stages (2 tiles in flight)
  float PBe[8], PBo[8];                    // B raw stages
  u32x4 a_h[2], a_l[2];                    // current A fragments (2 m-subtiles)

  auto LOADA = [&](float4* pa, int n0) {
    const float* ep = E + arow + n0 + kofs;
    pa[0] = *(const float4*)ep;
    pa[1] = *(const float4*)(ep + 4);
    const float* ep2 = ep + (size_t)16 * N_;
    pa[2] = *(const float4*)ep2;
    pa[3] = *(const float4*)(ep2 + 4);
  };
  auto LOADB = [&](float* pb, int n0) {
    const float* fp = F + (size_t)(n0 + (g << 3)) * C_ + c0 + cl;
#pragma unroll
    for (int j = 0; j < 8; ++j) pb[j] = fp[(size_t)j * C_];
  };
  auto SPLITA = [&](const float4* pa) {
#pragma unroll
    for (int mt = 0; mt < 2; ++mt) {
      unsigned h0, l0, h1, l1, h2, l2, h3, l3;
      split2(pa[2 * mt].x, pa[2 * mt].y, h0, l0);
      split2(pa[2 * mt].z, pa[2 * mt].w, h1, l1);
      split2(pa[2 * mt + 1].x, pa[2 * mt + 1].y, h2, l2);
      split2(pa[2 * mt + 1].z, pa[2 * mt + 1].w, h3, l3);
      a_h[mt] = (u32x4){h0, h1, h2, h3};
      a_l[mt] = (u32x4){l0, l1, l2, l3};
    }
  };
  auto WRITEB = [&](int p, const float* pb) {
    unsigned h0, l0, h1, l1, h2, l2, h3, l3;
    split2(pb[0], pb[1], h0, l0);
    split2(pb[2], pb[3], h1, l1);
    split2(pb[4], pb[5], h2, l2);
    split2(pb[6], pb[7], h3, l3);
    *(u32x4*)&BhL[p][slot4] = (u32x4){h0, h1, h2, h3};
    *(u32x4*)&BlL[p][slot4] = (u32x4){l0, l1, l2, l3};
  };
  auto COMPUTE = [&](int p) {
#pragma unroll
    for (int ct = 0; ct < 4; ++ct) {
      const short8_t b_h = *(const short8_t*)&BhL[p][(ct << 8) + (lane << 2)];
      const short8_t b_l = *(const short8_t*)&BlL[p][(ct << 8) + (lane << 2)];
#pragma unroll
      for (int mt = 0; mt < 2; ++mt) {
        const short8_t ah = __builtin_bit_cast(short8_t, a_h[mt]);
        const short8_t al = __builtin_bit_cast(short8_t, a_l[mt]);
        acc[mt][ct] = __builtin_amdgcn_mfma_f32_16x16x32_bf16(ah, b_h, acc[mt][ct], 0, 0, 0);
        acc[mt][ct] = __builtin_amdgcn_mfma_f32_16x16x32_bf16(al, b_h, acc[mt][ct], 0, 0, 0);
        acc[mt][ct] = __builtin_amdgcn_mfma_f32_16x16x32_bf16(ah, b_l, acc[mt][ct], 0, 0, 0);
      }
    }
  };

  // prologue
  LOADA(PAe, nb); LOADB(PBe, nb);
  if (nt > 1) { LOADA(PAo, nb + 32); LOADB(PBo, nb + 32); }
  WRITEB(0, PBe);        // waits tile-0 B loads
  SPLITA(PAe);           // waits tile-0 A loads
  KFENCE();

  for (int it = 0; it < nt; it += 2) {
    // even step: compute tile it from buf0; publish tile it+1; load tile it+2
    if (it + 1 < nt) WRITEB(1, PBo);                   // B(it+1), loaded 1 step ago
    if (it + 2 < nt) { LOADA(PAe, nb + ((it + 2) << 5)); LOADB(PBe, nb + ((it + 2) << 5)); }
    COMPUTE(0);
    if (it + 1 < nt) SPLITA(PAo);                      // A(it+1) -> frags
    KFENCE();
    if (it + 1 < nt) {
      if (it + 2 < nt) WRITEB(0, PBe);                 // B(it+2)
      if (it + 3 < nt) { LOADA(PAo, nb + ((it + 3) << 5)); LOADB(PBo, nb + ((it + 3) << 5)); }
      COMPUTE(1);
      if (it + 2 < nt) SPLITA(PAe);                    // A(it+2) -> frags
      KFENCE();
    }
  }

  // epilogue: C/D layout col=lane&15 (c), row=(lane>>4)*4+r (m)
  float* __restrict__ P = part + ((size_t)bm * Sa + s) * (K_ * C_);
#pragma unroll
  for (int mt = 0; mt < 2; ++mt)
#pragma unroll
    for (int ct = 0; ct < 4; ++ct) {
      const int ccol = c0 + (ct << 4) + lr;
#pragma unroll
      for (int r = 0; r < 4; ++r) {
        const int mrow = (wm << 5) + (mt << 4) + (lg << 2) + r;
        P[(size_t)mrow * C_ + ccol] = acc[mt][ct][r];
      }
    }
}

// ---------------------------------------------------------------------------
// Kernel 2: reduce split-n partials -> AB (float4 vectorized)
// ---------------------------------------------------------------------------
__global__ void reduce_parts(const float* __restrict__ part, float* __restrict__ AB, int Sa) {
  const int idx4 = blockIdx.x * 256 + threadIdx.x;       // float4 units
  if (idx4 >= 16 * K_ * C_ / 4) return;
  const int per = K_ * C_ / 4;
  const int bm = idx4 / per;
  const int rem4 = idx4 - bm * per;
  float4 v = {0.f, 0.f, 0.f, 0.f};
  for (int s = 0; s < Sa; ++s) {
    const float4 p = *(const float4*)&part[((size_t)bm * Sa + s) * (K_ * C_) + rem4 * 4];
    v.x += p.x; v.y += p.y; v.z += p.z; v.w += p.w;
  }
  *(float4*)&AB[(size_t)idx4 * 4] = v;
}

// ---------------------------------------------------------------------------
// Kernel 3: gram matrices, 64x64 quadrant per block (8 x 2 x 4 grid).
// which=0: Sm = A A^T + 1e-8 I ; which=1: Rm = Bm A^T
// ---------------------------------------------------------------------------
__global__ __launch_bounds__(256)
void gram_kernel(const float* __restrict__ AB, float* __restrict__ Sm, float* __restrict__ Rm) {
  const int b = blockIdx.x, which = blockIdx.y, qz = blockIdx.z;
  const int iq = (qz & 1) << 6, jq = (qz >> 1) << 6;
  const float* __restrict__ L  = AB + ((size_t)(b * 2 + which)) * (K_ * C_);
  const float* __restrict__ Ar = AB + ((size_t)(b * 2)) * (K_ * C_);
  float* __restrict__ out = (which ? Rm : Sm) + (size_t)b * (K_ * K_);
  const int t = threadIdx.x;
  const int ir = iq + ((t >> 4) << 2), jc = jq + ((t & 15) << 2);
  float acc[4][4] = {};
  for (int c0 = 0; c0 < C_; c0 += 4) {
    float4 li[4], rj[4];
#pragma unroll
    for (int i = 0; i < 4; ++i) li[i] = *(const float4*)(L + (size_t)(ir + i) * C_ + c0);
#pragma unroll
    for (int j = 0; j < 4; ++j) rj[j] = *(const float4*)(Ar + (size_t)(jc + j) * C_ + c0);
#pragma unroll
    for (int i = 0; i < 4; ++i)
#pragma unroll
      for (int j = 0; j < 4; ++j)
        acc[i][j] += li[i].x * rj[j].x + li[i].y * rj[j].y +
                     li[i].z * rj[j].z + li[i].w * rj[j].w;
  }
#pragma unroll
  for (int i = 0; i < 4; ++i)
#pragma unroll
    for (int j = 0; j < 4; ++j) {
      float v = acc[i][j];
      if (!which && (ir + i) == (jc + j)) v += 1e-8f;
      out[(size_t)(ir + i) * K_ + (jc + j)] = v;
    }
}

// ---------------------------------------------------------------------------
// Kernel 4: mask prep -> q1,p1 (cols, evals_x), q2,p2 (rows, evals_y)
// ---------------------------------------------------------------------------
__global__ void mask_prep(const float* __restrict__ evx, const float* __restrict__ evy,
                          float* __restrict__ PQ) {
  const int b = blockIdx.x, t = threadIdx.x;  // 128 threads
  float e1 = evx[b * K_ + t];
  float e2 = evy[b * K_ + t];
  if (e1 != e1) e1 = EPS_EV;
  if (e2 != e2) e2 = EPS_EV;
  e1 = fminf(fmaxf(e1, EPS_EV), 1e6f);
  e2 = fminf(fmaxf(e2, EPS_EV), 1e6f);

  __shared__ float wmax[2];
  float v = fmaxf(e1, e2);
#pragma unroll
  for (int d = 1; d < 64; d <<= 1) v = fmaxf(v, __shfl_xor(v, d, 64));
  if ((t & 63) == 0) wmax[t >> 6] = v;
  __syncthreads();
  const float scale = fmaxf(fmaxf(wmax[0], wmax[1]), 1e-10f);

  const float g1 = sqrtf(e1 / scale);
  const float g2 = sqrtf(e2 / scale);
  const float d1 = fmaf(g1, g1, 1.f);
  const float d2 = fmaf(g2, g2, 1.f);
  float* P = PQ + b * 512;
  P[t]       = g1 / d1;
  P[128 + t] = 1.f / d1;
  P[256 + t] = g2 / d2;
  P[384 + t] = 1.f / d2;
}

// ---------------------------------------------------------------------------
// Kernel 5: BLOCKED Gauss-Jordan inverse (SPD), 16x16 pivot panels, 512 thr.
// ---------------------------------------------------------------------------
__global__ __launch_bounds__(512)
void gj_inverse(const float* __restrict__ Sm, float* __restrict__ Sinv) {
  const int b = blockIdx.x, t = threadIdx.x;
  __shared__ float a[K_ * 132];
  __shared__ float Pi[16 * 20];
  __shared__ float Rp[16 * 132];
  __shared__ float Cp[K_ * 20];
  const float* __restrict__ Sb = Sm + (size_t)b * (K_ * K_);
#pragma unroll
  for (int l = 0; l < 8; ++l) {
    int f = t + (l << 9);
    int i = f >> 5, j = (f & 31) << 2;
    *(float4*)&a[i * 132 + j] = *(const float4*)(Sb + i * K_ + j);
  }
  __syncthreads();

  const int j = t & 127, rr = t >> 7;   // rr in 0..3
  const int lane = t & 63;

  for (int p = 0; p < 8; ++p) {
    const int pb = p << 4;

    if (t < 64) {
      const int r = lane & 15, g = lane >> 4;
      float4 v4 = *(const float4*)&a[(pb + r) * 132 + pb + (g << 2)];
      float vv[4] = {v4.x, v4.y, v4.z, v4.w};
#pragma unroll
      for (int k = 0; k < 16; ++k) {
        const int srcrow = (lane & 48) | k;
        float rk[4];
        rk[0] = __shfl(vv[0], srcrow);
        rk[1] = __shfl(vv[1], srcrow);
        rk[2] = __shfl(vv[2], srcrow);
        rk[3] = __shfl(vv[3], srcrow);
        const int kg = (k >> 2) << 4;
        const float pv = __shfl(vv[k & 3], kg | k);
        const float c  = __shfl(vv[k & 3], kg | r);
        const float pr = 1.0f / pv;
        float rs[4];
#pragma unroll
        for (int e = 0; e < 4; ++e) rs[e] = rk[e] * pr;
        if (r == k) {
#pragma unroll
          for (int e = 0; e < 4; ++e) vv[e] = rs[e];
          if (g == (k >> 2)) vv[k & 3] = pr;
        } else {
#pragma unroll
          for (int e = 0; e < 4; ++e) vv[e] = fmaf(-c, rs[e], vv[e]);
          if (g == (k >> 2)) vv[k & 3] = -c * pr;
        }
      }
      Pi[r * 20 + (g << 2) + 0] = vv[0];
      Pi[r * 20 + (g << 2) + 1] = vv[1];
      Pi[r * 20 + (g << 2) + 2] = vv[2];
      Pi[r * 20 + (g << 2) + 3] = vv[3];
    }
    __syncthreads();

    {
      float Ak[16];
#pragma unroll
      for (int k = 0; k < 16; ++k) Ak[k] = a[(pb + k) * 132 + j];
      const unsigned jj = (unsigned)(j - pb);
      const int r0 = rr << 2;
#pragma unroll
      for (int q = 0; q < 4; ++q) {
        const int r = r0 + q;
        float acc = 0.f;
#pragma unroll
        for (int k = 0; k < 16; ++k) acc = fmaf(Pi[r * 20 + k], Ak[k], acc);
        Rp[r * 132 + j] = (jj < 16u) ? Pi[r * 20 + jj] : acc;
      }
      const int i = j;
      const int cb = rr << 2;
      float4 cA = *(const float4*)&a[i * 132 + pb + cb];
      *(float4*)&Cp[i * 20 + cb] = cA;
    }
    __syncthreads();

    {
      float Rk[16];
#pragma unroll
      for (int k = 0; k < 16; ++k) Rk[k] = Rp[k * 132 + j];
      const unsigned jj = (unsigned)(j - pb);
      const int i0 = rr << 5;
#pragma unroll 4
      for (int m = 0; m < 32; ++m) {
        const int i = i0 + m;
        const float4 c0 = *(const float4*)&Cp[i * 20];
        const float4 c1 = *(const float4*)&Cp[i * 20 + 4];
        const float4 c2 = *(const float4*)&Cp[i * 20 + 8];
        const float4 c3 = *(const float4*)&Cp[i * 20 + 12];
        float u0 = c0.x * Rk[0] + c0.y * Rk[1] + c0.z * Rk[2] + c0.w * Rk[3];
        float u1 = c1.x * Rk[4] + c1.y * Rk[5] + c1.z * Rk[6] + c1.w * Rk[7];
        float u2 = c2.x * Rk[8] + c2.y * Rk[9] + c2.z * Rk[10] + c2.w * Rk[11];
        float u3 = c3.x * Rk[12] + c3.y * Rk[13] + c3.z * Rk[14] + c3.w * Rk[15];
        const float upd = (u0 + u1) + (u2 + u3);
        const unsigned ii = (unsigned)(i - pb);
        float newv;
        if (ii < 16u) {
          newv = Rk[ii];
        } else {
          const float base = (jj < 16u) ? 0.f : a[i * 132 + j];
          newv = base - upd;
        }
        a[i * 132 + j] = newv;
      }
    }
    __syncthreads();
  }

  float* __restrict__ O = Sinv + (size_t)b * (K_ * K_);
#pragma unroll
  for (int l = 0; l < 8; ++l) {
    int f = t + (l << 9);
    int i = f >> 5, jq = (f & 31) << 2;
    *(float4*)(O + i * K_ + jq) = *(const float4*)&a[i * 132 + jq];
  }
}

// ---------------------------------------------------------------------------
// Kernel 6: Neumann iteration, 4 blocks per batch (32 rows each).
// Xout = (R - W .* Xin) @ Sinv ; W[i,k]=LMBDA*((q2i-q1k)^2+(p2i-p1k)^2)
// ---------------------------------------------------------------------------
__global__ __launch_bounds__(256)
void solve_iter(const float* __restrict__ Rm, const float* __restrict__ Sinv,
                const float* __restrict__ PQ, const float* __restrict__ Xin,
                float* __restrict__ Xout, const int first) {
  const int bb = blockIdx.x;
  const int b = bb >> 2, rb = (bb & 3) << 5;
  const int t = threadIdx.x;
  __shared__ float Tt[32][34];
  __shared__ float Sv[32][132];
  __shared__ float q1[K_], p1[K_], q2l[32], p2l[32];
  {
    const float* P = PQ + b * 512;
    if (t < K_) { q1[t] = P[t]; p1[t] = P[128 + t]; }
    if (t < 32) { q2l[t] = P[256 + rb + t]; p2l[t] = P[384 + rb + t]; }
  }
  __syncthreads();
  const float* __restrict__ Rb = Rm + (size_t)b * (K_ * K_);
  const float* __restrict__ Xb = Xin + (size_t)b * (K_ * K_);
  const float* __restrict__ Si = Sinv + (size_t)b * (K_ * K_);
  const int ir = (t >> 4) << 1, jc = (t & 15) << 3;
  float acc[2][8] = {};

  for (int k0 = 0; k0 < K_; k0 += 32) {
    {
      const int i = t >> 3;            // 0..31
      const int kk = (t & 7) << 2;
      const int k = k0 + kk;
      const int gi = rb + i;
      float4 tv = *(const float4*)(Rb + (size_t)gi * K_ + k);
      if (!first) {
        const float4 x4 = *(const float4*)(Xb + (size_t)gi * K_ + k);
        const float qi = q2l[i], pi = p2l[i];
        float dq, dp, w;
        dq = qi - q1[k + 0]; dp = pi - p1[k + 0]; w = fmaf(dq, dq, dp * dp);
        tv.x = fmaf(-LMBDA * w, x4.x, tv.x);
        dq = qi - q1[k + 1]; dp = pi - p1[k + 1]; w = fmaf(dq, dq, dp * dp);
        tv.y = fmaf(-LMBDA * w, x4.y, tv.y);
        dq = qi - q1[k + 2]; dp = pi - p1[k + 2]; w = fmaf(dq, dq, dp * dp);
        tv.z = fmaf(-LMBDA * w, x4.z, tv.z);
        dq = qi - q1[k + 3]; dp = pi - p1[k + 3]; w = fmaf(dq, dq, dp * dp);
        tv.w = fmaf(-LMBDA * w, x4.w, tv.w);
      }
      Tt[kk + 0][i] = tv.x; Tt[kk + 1][i] = tv.y;
      Tt[kk + 2][i] = tv.z; Tt[kk + 3][i] = tv.w;
    }
#pragma unroll
    for (int l = 0; l < 4; ++l) {
      int f = t + (l << 8);
      int kk = f >> 5, j4 = (f & 31) << 2;
      *(float4*)&Sv[kk][j4] = *(const float4*)(Si + (size_t)(k0 + kk) * K_ + j4);
    }
    __syncthreads();
#pragma unroll
    for (int kk = 0; kk < 32; ++kk) {
      const float2 a2 = *(const float2*)&Tt[kk][ir];
      const float4 b0 = *(const float4*)&Sv[kk][jc];
      const float4 b1 = *(const float4*)&Sv[kk][jc + 4];
      const float bv[8] = {b0.x, b0.y, b0.z, b0.w, b1.x, b1.y, b1.z, b1.w};
#pragma unroll
      for (int jx = 0; jx < 8; ++jx) {
        acc[0][jx] = fmaf(a2.x, bv[jx], acc[0][jx]);
        acc[1][jx] = fmaf(a2.y, bv[jx], acc[1][jx]);
      }
    }
    __syncthreads();
  }

  float* __restrict__ O = Xout + (size_t)b * (K_ * K_);
#pragma unroll
  for (int i = 0; i < 2; ++i) {
    float4 o0 = {acc[i][0], acc[i][1], acc[i][2], acc[i][3]};
    float4 o1 = {acc[i][4], acc[i][5], acc[i][6], acc[i][7]};
    *(float4*)(O + (size_t)(rb + ir + i) * K_ + jc) = o0;
    *(float4*)(O + (size_t)(rb + ir + i) * K_ + jc + 4) = o1;
  }
}

// ---------------------------------------------------------------------------
extern "C" void kernel_launch(void* const* d_in, const int* in_sizes, int n_in,
                              void* d_out, int out_size, void* d_ws, size_t ws_size,
                              hipStream_t stream) {
  (void)in_sizes; (void)n_in; (void)out_size;
  const float* feat_x  = (const float*)d_in[0];
  const float* feat_y  = (const float*)d_in[1];
  const float* evals_x = (const float*)d_in[2];
  const float* evals_y = (const float*)d_in[3];
  const float* evtx    = (const float*)d_in[4];
  const float* evty    = (const float*)d_in[5];
  float* out = (float*)d_out;
  float* ws  = (float*)d_ws;

  const size_t KC16 = (size_t)16 * K_ * C_;  // 524288 floats
  const size_t KK   = (size_t)K_ * K_;       // 16384
  const size_t fixed = KC16 + 3 * (KK * B_) + 4096 + 2 * (KK * B_);
  const int T = N_ / 32;  // 625 k-steps total

  int S = 16, Sa = 16, chunk = 0;
  for (;;) {
    int steps = (T + S - 1) / S;
    chunk = steps * 32;
    Sa = (T + steps - 1) / steps;  // active slabs, all with nb < N_
    if (((size_t)Sa * KC16 + fixed) * sizeof(float) <= ws_size || S == 1) break;
    S >>= 1;
  }

  float* part = ws;
  float* AB   = part + (size_t)Sa * KC16;
  float* Sm   = AB + KC16;
  float* Rm   = Sm + KK * B_;
  float* Sinv = Rm + KK * B_;
  float* PQ   = Sinv + KK * B_;
  float* X0   = PQ + 4096;
  float* X1   = X0 + KK * B_;

  mask_prep<<<dim3(8), 128, 0, stream>>>(evals_x, evals_y, PQ);
  proj_mfma<<<dim3(4, Sa, 16), 256, 0, stream>>>(feat_x, feat_y, evtx, evty, part, Sa, chunk);
  reduce_parts<<<dim3(16 * K_ * C_ / 4 / 256), 256, 0, stream>>>(part, AB, Sa);
  gram_kernel<<<dim3(8, 2, 4), 256, 0, stream>>>(AB, Sm, Rm);
  gj_inverse<<<dim3(8), 512, 0, stream>>>(Sm, Sinv);
  solve_iter<<<dim3(32), 256, 0, stream>>>(Rm, Sinv, PQ, X0, X0, 1);
  solve_iter<<<dim3(32), 256, 0, stream>>>(Rm, Sinv, PQ, X0, X1, 0);
  solve_iter<<<dim3(32), 256, 0, stream>>>(Rm, Sinv, PQ, X1, out, 0);
}